// Round 12
// baseline (484.131 us; speedup 1.0000x reference)
//
#include <hip/hip_runtime.h>
#include <hip/hip_bf16.h>
#include <math.h>

// Problem constants
#define L_ 1024
#define B_ 4
#define D_ 1024
#define E_ 8
#define K_ 2
#define H_ 4096
#define T_ (L_*B_)        // 4096 tokens
#define P_ (T_*K_)        // 8192 token-expert pairs
#define PPAD (P_+256)     // padded rows so partial 256-tiles can over-read safely

typedef unsigned short u16;
typedef __attribute__((ext_vector_type(4))) float f32x4;
typedef __attribute__((ext_vector_type(8))) short s16x8;

__device__ __forceinline__ u16 f2bf(float f) {
  uint32_t u = __float_as_uint(f);
  uint32_t r = (u + 0x7FFFu + ((u >> 16) & 1u)) >> 16;  // RNE
  return (u16)r;
}
__device__ __forceinline__ float bf2f(u16 v) {
  return __uint_as_float((uint32_t)v << 16);
}
// gelu tanh-approx in sigmoid form
__device__ __forceinline__ float gelu_fast(float v) {
  float u = v * (1.0f + 0.044715f * v * v);
  float t = __expf(-1.5957691216057308f * u);
  return v / (1.0f + t);
}

// ---------------------------------------------------------------------------
// meta layout (ints): counts[0:8) offs[8:16) cursors[16:24) nbx[24:32)
//                     ub1[32:41) ub2[41:50) tick1@50 tick2@51
// ---------------------------------------------------------------------------

// ---------------------------------------------------------------------------
// PREP (fused): blocks [0,8192): w1 fp32(D,H)->bf16(H,D); [8192,16384): w2
// fp32(H,D)->bf16(D,H); [16384,17408): gating. All independent.
// ---------------------------------------------------------------------------
__device__ void conv_block(const float* __restrict__ src, u16* __restrict__ dst,
                           int R, int C, int r0, int c0) {
  __shared__ float tile[64][65];
  int t = threadIdx.x;
  int tr = t >> 4, tc = (t & 15) * 4;
#pragma unroll
  for (int p = 0; p < 4; ++p) {
    int r = tr + p * 16;
    float4 v = *(const float4*)(src + (size_t)(r0 + r) * C + c0 + tc);
    tile[r][tc] = v.x; tile[r][tc+1] = v.y; tile[r][tc+2] = v.z; tile[r][tc+3] = v.w;
  }
  __syncthreads();
#pragma unroll
  for (int p = 0; p < 4; ++p) {
    int c = tr + p * 16;
    ushort4 o;
    o.x = f2bf(tile[tc+0][c]); o.y = f2bf(tile[tc+1][c]);
    o.z = f2bf(tile[tc+2][c]); o.w = f2bf(tile[tc+3][c]);
    *(ushort4*)(dst + (size_t)(c0 + c) * R + r0 + tc) = o;
  }
}

__global__ void prep(const float* __restrict__ w1, u16* __restrict__ w1b,
                     const float* __restrict__ w2, u16* __restrict__ w2b,
                     const float* __restrict__ x, const float* __restrict__ task_param,
                     const float* __restrict__ gw_img, const float* __restrict__ gb_img,
                     const float* __restrict__ gw_txt, const float* __restrict__ gb_txt,
                     const float* __restrict__ tgw, const float* __restrict__ tgb,
                     const float* __restrict__ alpha_p, const int* __restrict__ is_text_p,
                     float4* __restrict__ sel_w, float* __restrict__ prob_part,
                     int* __restrict__ count_part) {
  int gid = blockIdx.x;
  if (gid < 8192) {
    // w1: R=D, C=H; grid (x:H/64=64, y:D/64=16, e:8)
    int gx = gid & 63, gy = (gid >> 6) & 15, e = gid >> 10;
    conv_block(w1 + (size_t)e * D_ * H_, w1b + (size_t)e * D_ * H_,
               D_, H_, gy * 64, gx * 64);
    return;
  }
  if (gid < 16384) {
    int g = gid - 8192;
    // w2: R=H, C=D; grid (x:D/64=16, y:H/64=64, e:8)
    int gx = g & 15, gy = (g >> 4) & 63, e = g >> 10;
    conv_block(w2 + (size_t)e * D_ * H_, w2b + (size_t)e * D_ * H_,
               H_, D_, gy * 64, gx * 64);
    return;
  }
  // ---- gating: one wave per token ----
  int bid = gid - 16384;
  __shared__ float wprob[4][8];
  __shared__ int wcnt[4][8];
  int wid = threadIdx.x >> 6, lane = threadIdx.x & 63;
  int t = bid * 4 + wid;
  int b = t & (B_ - 1);
  int it = is_text_p[0];
  const float* gw = it ? gw_txt : gw_img;
  const float* gb = it ? gb_txt : gb_img;
  float alpha = alpha_p[0];
  const float* xr = x + (size_t)t * D_;
  const float* tp = task_param + (size_t)b * D_;
  float acc[8] = {0,0,0,0,0,0,0,0};
  float tac[8] = {0,0,0,0,0,0,0,0};
  for (int i = 0; i < D_/64; ++i) {
    int d = i * 64 + lane;
    float xv = xr[d], tv = tp[d];
#pragma unroll
    for (int e = 0; e < 8; ++e) {
      acc[e] += xv * gw[d*8 + e];
      tac[e] += tv * tgw[d*8 + e];
    }
  }
#pragma unroll
  for (int e = 0; e < 8; ++e) {
#pragma unroll
    for (int off = 32; off > 0; off >>= 1) {
      acc[e] += __shfl_xor(acc[e], off);
      tac[e] += __shfl_xor(tac[e], off);
    }
  }
  float lg[8];
#pragma unroll
  for (int e = 0; e < 8; ++e)
    lg[e] = (1.0f - alpha) * (acc[e] + gb[e]) + alpha * (tac[e] + tgb[e]);
  float m = lg[0];
#pragma unroll
  for (int e = 1; e < 8; ++e) m = fmaxf(m, lg[e]);
  float pr[8], ps = 0.f;
#pragma unroll
  for (int e = 0; e < 8; ++e) { pr[e] = expf(lg[e] - m); ps += pr[e]; }
  float inv = 1.0f / ps;
  int i0 = 0; float v0 = lg[0];
#pragma unroll
  for (int e = 1; e < 8; ++e) if (lg[e] > v0) { v0 = lg[e]; i0 = e; }
  int i1 = -1; float v1 = -1e30f;
#pragma unroll
  for (int e = 0; e < 8; ++e) if (e != i0 && lg[e] > v1) { v1 = lg[e]; i1 = e; }
  float ex = expf(v1 - v0);
  float w0 = 1.0f / (1.0f + ex), w1v = ex / (1.0f + ex);
  if (lane == 0) {
    sel_w[t] = make_float4(__int_as_float(i0), __int_as_float(i1), w0, w1v);
#pragma unroll
    for (int e = 0; e < 8; ++e) {
      wprob[wid][e] = pr[e] * inv;
      wcnt[wid][e] = (i0 == e) + (i1 == e);
    }
  }
  __syncthreads();
  if (threadIdx.x < 8) {
    int e = threadIdx.x;
    prob_part[bid * 8 + e] = wprob[0][e] + wprob[1][e] + wprob[2][e] + wprob[3][e];
    count_part[bid * 8 + e] = wcnt[0][e] + wcnt[1][e] + wcnt[2][e] + wcnt[3][e];
  }
}

// ---------------------------------------------------------------------------
// Finalize: deterministic reduce -> counts/offs/cursors + unit tables + l_aux
// ---------------------------------------------------------------------------
__global__ void finalize(const float* __restrict__ prob_part, const int* __restrict__ count_part,
                         int* __restrict__ meta, float* __restrict__ laux_out) {
  __shared__ float ps_[256];
  __shared__ int cs_[256];
  int t = threadIdx.x;
  int e = t & 7, s = t >> 3;
  float p = 0.f; int c = 0;
  for (int b = s; b < 1024; b += 32) { p += prob_part[b*8 + e]; c += count_part[b*8 + e]; }
  ps_[t] = p; cs_[t] = c;
  __syncthreads();
  for (int st = 16; st > 0; st >>= 1) {
    if (s < st) { ps_[t] += ps_[t + st*8]; cs_[t] += cs_[t + st*8]; }
    __syncthreads();
  }
  if (t == 0) {
    int off = 0; float laux = 0.f;
    int u1 = 0, u2 = 0;
    for (int ee = 0; ee < 8; ++ee) {
      int cnt = cs_[ee];
      meta[ee] = cnt;          // counts
      meta[8 + ee] = off;      // offs
      meta[16 + ee] = off;     // cursors
      int nb = (cnt + 255) >> 8;
      meta[24 + ee] = nb;      // nbx
      meta[32 + ee] = u1;      // ub1 (GEMM1: 16 panels x nb)
      meta[41 + ee] = u2;      // ub2 (GEMM2: 4 panels x nb x 2 ksplit)
      u1 += 16 * nb;
      u2 += 4 * nb * 2;
      off += cnt;
      laux += (ps_[ee] * (1.0f/4096.0f)) * ((float)cnt * (1.0f/4096.0f));
    }
    meta[32 + 8] = u1;         // ub1[8] = U1 total
    meta[41 + 8] = u2;         // ub2[8] = U2 total
    meta[50] = 0;              // tick1
    meta[51] = 0;              // tick2
    *laux_out = laux;
  }
}

// ---------------------------------------------------------------------------
// Scatter + gather: assign bucket slots, record token->pair map, gather bf16 rows
// ---------------------------------------------------------------------------
__global__ void scatter_gather(const float* __restrict__ x, const float4* __restrict__ sel_w,
                               int* __restrict__ cursors, float* __restrict__ pair_w,
                               int* __restrict__ pair_idx, u16* __restrict__ Xg) {
  int wid = threadIdx.x >> 6, lane = threadIdx.x & 63;
  int t = blockIdx.x * 4 + wid;
  float4 sw = sel_w[t];
  int s0 = __float_as_int(sw.x), s1 = __float_as_int(sw.y);
  int p0 = 0, p1 = 0;
  if (lane == 0) {
    p0 = atomicAdd(&cursors[s0], 1);
    p1 = atomicAdd(&cursors[s1], 1);
  }
  p0 = __shfl(p0, 0); p1 = __shfl(p1, 0);
  if (lane == 0) {
    pair_w[p0] = sw.z; pair_w[p1] = sw.w;
    pair_idx[t*2] = p0; pair_idx[t*2+1] = p1;
  }
  const float* xr = x + (size_t)t * D_;
  u16* d0 = Xg + (size_t)p0 * D_;
  u16* d1 = Xg + (size_t)p1 * D_;
#pragma unroll
  for (int i = 0; i < 4; ++i) {
    int c = i * 256 + lane * 4;
    float4 v = *(const float4*)(xr + c);
    ushort4 o;
    o.x = f2bf(v.x); o.y = f2bf(v.y); o.z = f2bf(v.z); o.w = f2bf(v.w);
    *(ushort4*)(d0 + c) = o;
    *(ushort4*)(d1 + c) = o;
  }
}

// ---------------------------------------------------------------------------
// Grouped GEMM, 256x256 tile, BK=64, 8 waves, 2-phase double-buffer,
// DYNAMIC TICKET dispatch — byte-identical to R10's verified 155 µs config
// except the EPI==1 epilogue writes bf16 parts (halves write+combine traffic).
//
// Schedule scoreboard (this session): 2ph-BK64 155 > 8ph 185 > BK32-2ph 208 >
// ring-BK32 215 µs. Depth-2 at BK64 cannot fit LDS (3x64KB > 160KB, R11).
// L2-hot operands (R10 FETCH 122MB vs 2.1GB logical) mean staging latency is
// ~200cy, covered by the iter's ds_read+MFMA; the 2ph rhythm cost is
// structural and 8ph measured neutral on this grouped shape.
//
// LDS swizzle (verified 0 conflicts): 8 x 16B slots/row, phys = kk^(row&7);
// staging dest linear in tid (rule 21), global source carries the inverse.
// __launch_bounds__(512,2): CUDA min-blocks semantics -> VGPR cap 128.
// ---------------------------------------------------------------------------
template<int EPI, int KDIM, int KLEN, int NOUT, int NPANEL, int KSPLIT>
__global__ __launch_bounds__(512, 2)
void gemm256(const u16* __restrict__ Tok, const u16* __restrict__ Wt,
             int* __restrict__ meta, const float* __restrict__ pair_w,
             u16* __restrict__ Hout, u16* __restrict__ Cout) {
  const int* offs = meta + 8;
  const int* nbx  = meta + 24;
  const int* ub   = (EPI == 0) ? meta + 32 : meta + 41;
  int* tick       = meta + ((EPI == 0) ? 50 : 51);

  __shared__ u16 As[2][16384];   // 256 x 64 bf16 = 32 KB per buffer
  __shared__ u16 Bs[2][16384];
  __shared__ int s_u;
  int t = threadIdx.x, lane = t & 63, wid = t >> 6;
  int wf = wid & 1, wt = wid >> 1;

  // staging map: i covers slots [i*512 + t]; row = slot>>3,
  // kk = (slot&7) ^ (row&7) (involution).
  int goff[4]; int ldso[4];
#pragma unroll
  for (int i = 0; i < 4; ++i) {
    int slot = i * 512 + t;
    int row = slot >> 3;
    int kk = (slot & 7) ^ (row & 7);
    goff[i] = row * KDIM + kk * 8;
    ldso[i] = slot * 8;
  }

  // fragment read offsets (u16): phys = (row*8 + (kk ^ (row&7)))*8
  int aoff[8][2], boff[4][2];
#pragma unroll
  for (int r = 0; r < 8; ++r) {
    int row = wf * 128 + r * 16 + (lane & 15);
#pragma unroll
    for (int h = 0; h < 2; ++h) {
      int kk = h * 4 + (lane >> 4);
      aoff[r][h] = (row * 8 + (kk ^ (row & 7))) * 8;
    }
  }
#pragma unroll
  for (int f = 0; f < 4; ++f) {
    int row = wt * 64 + f * 16 + (lane & 15);
#pragma unroll
    for (int h = 0; h < 2; ++h) {
      int kk = h * 4 + (lane >> 4);
      boff[f][h] = (row * 8 + (kk ^ (row & 7))) * 8;
    }
  }

  constexpr int NT = KLEN / 64;
  int lr = lane & 15, lg4 = (lane >> 4) * 4;
  int Utot = ub[8];

  for (;;) {
    if (t == 0) s_u = atomicAdd(tick, 1);
    __syncthreads();               // broadcast ticket; also fences LDS reuse
    int u = s_u;
    if (u >= Utot) break;
    // decode unit: expert (8-entry prefix scan), then panel-major local
    int e = 0;
    while (u >= ub[e + 1]) ++e;
    int ul = u - ub[e];
    int nb = nbx[e];
    int panel = ul / (nb * KSPLIT);
    int rem   = ul - panel * (nb * KSPLIT);
    int bx    = rem / KSPLIT;
    int ks    = rem - bx * KSPLIT;
    int ne  = meta[e];
    int off = offs[e];
    int kbase = ks * KLEN;
    u16* Cpart = Cout + (size_t)ks * P_ * D_;
    const u16* Wg = Wt + (size_t)e * NOUT * KDIM + (size_t)panel * 256 * KDIM + kbase;
    const u16* Tg = Tok + (size_t)(off + bx * 256) * KDIM + kbase;

    f32x4 acc[8][4] = {};
    // prologue: stage K-tile 0 into buf 0
#pragma unroll
    for (int i = 0; i < 4; ++i) {
      __builtin_amdgcn_global_load_lds(
          (const __attribute__((address_space(1))) void*)(Wg + goff[i]),
          (__attribute__((address_space(3))) void*)(&As[0][ldso[i]]), 16, 0, 0);
      __builtin_amdgcn_global_load_lds(
          (const __attribute__((address_space(1))) void*)(Tg + goff[i]),
          (__attribute__((address_space(3))) void*)(&Bs[0][ldso[i]]), 16, 0, 0);
    }
    __syncthreads();
    int cur = 0;
    for (int tt = 0; tt < NT; ++tt) {
      if (tt + 1 < NT) {
        int k0 = (tt + 1) * 64;
        int nbuf = cur ^ 1;
#pragma unroll
        for (int i = 0; i < 4; ++i) {
          __builtin_amdgcn_global_load_lds(
              (const __attribute__((address_space(1))) void*)(Wg + goff[i] + k0),
              (__attribute__((address_space(3))) void*)(&As[nbuf][ldso[i]]), 16, 0, 0);
          __builtin_amdgcn_global_load_lds(
              (const __attribute__((address_space(1))) void*)(Tg + goff[i] + k0),
              (__attribute__((address_space(3))) void*)(&Bs[nbuf][ldso[i]]), 16, 0, 0);
        }
      }
      const u16* Ab = &As[cur][0]; const u16* Bb = &Bs[cur][0];
#pragma unroll
      for (int h = 0; h < 2; ++h) {
        s16x8 a[8], b[4];
#pragma unroll
        for (int r = 0; r < 8; ++r) a[r] = *(const s16x8*)(Ab + aoff[r][h]);
#pragma unroll
        for (int f = 0; f < 4; ++f) b[f] = *(const s16x8*)(Bb + boff[f][h]);
#pragma unroll
        for (int r = 0; r < 8; ++r)
#pragma unroll
          for (int f = 0; f < 4; ++f)
            acc[r][f] = __builtin_amdgcn_mfma_f32_16x16x32_bf16(a[r], b[f], acc[r][f], 0, 0, 0);
      }
      __syncthreads();
      cur ^= 1;
    }

    // epilogue: token = wt*64 + f*16 + lr (col), feature = wf*128 + r*16 + lg4 + j
#pragma unroll
    for (int f = 0; f < 4; ++f) {
      int tokl = bx * 256 + wt * 64 + f * 16 + lr;
      if (tokl >= ne) continue;
      size_t grow = (size_t)(off + tokl);
      if (EPI == 0) {
#pragma unroll
        for (int r = 0; r < 8; ++r) {
          ushort4 o;
          o.x = f2bf(gelu_fast(acc[r][f][0]));
          o.y = f2bf(gelu_fast(acc[r][f][1]));
          o.z = f2bf(gelu_fast(acc[r][f][2]));
          o.w = f2bf(gelu_fast(acc[r][f][3]));
          *(ushort4*)(Hout + grow * NOUT + panel * 256 + wf * 128 + r * 16 + lg4) = o;
        }
      } else {
        float w = pair_w[grow];
#pragma unroll
        for (int r = 0; r < 8; ++r) {
          ushort4 o;
          o.x = f2bf(acc[r][f][0] * w); o.y = f2bf(acc[r][f][1] * w);
          o.z = f2bf(acc[r][f][2] * w); o.w = f2bf(acc[r][f][3] * w);
          *(ushort4*)(Cpart + grow * NOUT + panel * 256 + wf * 128 + r * 16 + lg4) = o;
        }
      }
    }
  }
}

// ---------------------------------------------------------------------------
// Combine: out[token] = sum over 2 pairs x 2 K-parts (bf16 parts -> f32)
// ---------------------------------------------------------------------------
__global__ void combine(const u16* __restrict__ pair_out, const int* __restrict__ pair_idx,
                        float* __restrict__ out) {
  const u16* part1 = pair_out + (size_t)P_ * D_;
  int t = blockIdx.x;
  int p0 = pair_idx[t*2], p1 = pair_idx[t*2+1];
  int c = threadIdx.x * 4;
  ushort4 a0 = *(const ushort4*)(pair_out + (size_t)p0 * D_ + c);
  ushort4 a1 = *(const ushort4*)(part1    + (size_t)p0 * D_ + c);
  ushort4 b0 = *(const ushort4*)(pair_out + (size_t)p1 * D_ + c);
  ushort4 b1 = *(const ushort4*)(part1    + (size_t)p1 * D_ + c);
  float4 o;
  o.x = (bf2f(a0.x) + bf2f(a1.x)) + (bf2f(b0.x) + bf2f(b1.x));
  o.y = (bf2f(a0.y) + bf2f(a1.y)) + (bf2f(b0.y) + bf2f(b1.y));
  o.z = (bf2f(a0.z) + bf2f(a1.z)) + (bf2f(b0.z) + bf2f(b1.z));
  o.w = (bf2f(a0.w) + bf2f(a1.w)) + (bf2f(b0.w) + bf2f(b1.w));
  *(float4*)(out + (size_t)t * D_ + c) = o;
}

// ---------------------------------------------------------------------------
// Workspace layout (bytes):
//   w1b  [E][H][D] bf16 @ 0           (67108864)  <- aliased by pair_out parts
//   w2b  [E][D][H] bf16 @ 67108864    (67108864)
//   Xg   [PPAD][D] bf16 @ 134217728   (17301504)
//   Hb   [PPAD][H] bf16 @ 151519232   (69206016)
//   small buffers @ 220725248
//   pair_out: 2 parts x [P_][D_] bf16 @ 0 (33554432, aliases dead w1b)
// ---------------------------------------------------------------------------
extern "C" void kernel_launch(void* const* d_in, const int* in_sizes, int n_in,
                              void* d_out, int out_size, void* d_ws, size_t ws_size,
                              hipStream_t stream) {
  const float* inputs      = (const float*)d_in[0];
  const float* task_param  = (const float*)d_in[1];
  const float* gate_img_w  = (const float*)d_in[2];
  const float* gate_img_b  = (const float*)d_in[3];
  const float* gate_txt_w  = (const float*)d_in[4];
  const float* gate_txt_b  = (const float*)d_in[5];
  const float* task_gate_w = (const float*)d_in[6];
  const float* task_gate_b = (const float*)d_in[7];
  const float* alpha       = (const float*)d_in[8];
  const float* w1          = (const float*)d_in[9];
  const float* w2          = (const float*)d_in[10];
  const int*   is_text     = (const int*)d_in[11];
  float* out = (float*)d_out;

  char* ws = (char*)d_ws;
  u16* w1b = (u16*)(ws + 0);
  u16* w2b = (u16*)(ws + 67108864);
  u16* Xg  = (u16*)(ws + 134217728);
  u16* Hb  = (u16*)(ws + 151519232);
  float4* sel_w   = (float4*)(ws + 220725248);
  float* pair_w   = (float*)(ws + 220725248 + 65536);
  int* pair_idx   = (int*)(ws + 220725248 + 98816);
  float* prob_part= (float*)(ws + 220725248 + 131584);
  int* count_part = (int*)(ws + 220725248 + 164352);
  int* meta       = (int*)(ws + 220725248 + 197120);
  u16* pair_out   = (u16*)(ws + 0);  // 2 bf16 parts, aliases dead w1b

  // PREP: w1 conv (8192 blocks) + w2 conv (8192) + gating (1024), fused.
  prep<<<dim3(17408), 256, 0, stream>>>(w1, w1b, w2, w2b,
      inputs, task_param, gate_img_w, gate_img_b, gate_txt_w, gate_txt_b,
      task_gate_w, task_gate_b, alpha, is_text, sel_w, prob_part, count_part);
  finalize<<<dim3(1), 256, 0, stream>>>(prob_part, count_part, meta,
      out + (size_t)T_ * D_);
  scatter_gather<<<dim3(T_/4), 256, 0, stream>>>(inputs, sel_w, meta + 16, pair_w, pair_idx, Xg);
  // GEMM1: Tok=Xg, W=w1b; K=1024 (NT=16), 16 panels, no ksplit. Ticketed.
  gemm256<0, D_, D_, H_, 16, 1><<<dim3(256), 512, 0, stream>>>(
      Xg, w1b, meta, pair_w, Hb, (u16*)nullptr);
  // GEMM2: Tok=Hb, W=w2b; K=4096 split 2x2048 (NT=32), 4 panels. Ticketed.
  gemm256<1, H_, H_/2, D_, 4, 2><<<dim3(256), 512, 0, stream>>>(
      Hb, w2b, meta, pair_w, (u16*)nullptr, pair_out);
  combine<<<dim3(T_), 256, 0, stream>>>(pair_out, pair_idx, out);
}

// Round 13
// 449.029 us; speedup vs baseline: 1.0782x; 1.0782x over previous
//
#include <hip/hip_runtime.h>
#include <hip/hip_bf16.h>
#include <math.h>

// Problem constants
#define L_ 1024
#define B_ 4
#define D_ 1024
#define E_ 8
#define K_ 2
#define H_ 4096
#define T_ (L_*B_)        // 4096 tokens
#define P_ (T_*K_)        // 8192 token-expert pairs
#define PPAD (P_+256)     // padded rows so partial 256-tiles can over-read safely

typedef unsigned short u16;
typedef __attribute__((ext_vector_type(4))) float f32x4;
typedef __attribute__((ext_vector_type(8))) short s16x8;

__device__ __forceinline__ u16 f2bf(float f) {
  uint32_t u = __float_as_uint(f);
  uint32_t r = (u + 0x7FFFu + ((u >> 16) & 1u)) >> 16;  // RNE
  return (u16)r;
}
__device__ __forceinline__ float bf2f(u16 v) {
  return __uint_as_float((uint32_t)v << 16);
}
// gelu tanh-approx in sigmoid form
__device__ __forceinline__ float gelu_fast(float v) {
  float u = v * (1.0f + 0.044715f * v * v);
  float t = __expf(-1.5957691216057308f * u);
  return v / (1.0f + t);
}

// ---------------------------------------------------------------------------
// meta layout (ints): counts[0:8) offs[8:16) cursors[16:24) nbx[24:32)
//                     ub1[32:41) ub2[41:50) tick1@50 tick2@51
// ---------------------------------------------------------------------------

// ---------------------------------------------------------------------------
// PREP: blocks [0,8192): w1 fp32(D,H)->bf16(H,D) 64x64 tiles;
//       blocks [8192,9216): gating (one wave per token).
// (w2 conversion moved into GEMM1's ticket space as tail-fill units.)
// ---------------------------------------------------------------------------
__device__ void conv_block(const float* __restrict__ src, u16* __restrict__ dst,
                           int R, int C, int r0, int c0) {
  __shared__ float tile[64][65];
  int t = threadIdx.x;
  int tr = t >> 4, tc = (t & 15) * 4;
#pragma unroll
  for (int p = 0; p < 4; ++p) {
    int r = tr + p * 16;
    float4 v = *(const float4*)(src + (size_t)(r0 + r) * C + c0 + tc);
    tile[r][tc] = v.x; tile[r][tc+1] = v.y; tile[r][tc+2] = v.z; tile[r][tc+3] = v.w;
  }
  __syncthreads();
#pragma unroll
  for (int p = 0; p < 4; ++p) {
    int c = tr + p * 16;
    ushort4 o;
    o.x = f2bf(tile[tc+0][c]); o.y = f2bf(tile[tc+1][c]);
    o.z = f2bf(tile[tc+2][c]); o.w = f2bf(tile[tc+3][c]);
    *(ushort4*)(dst + (size_t)(c0 + c) * R + r0 + tc) = o;
  }
}

__global__ void prep(const float* __restrict__ w1, u16* __restrict__ w1b,
                     const float* __restrict__ x, const float* __restrict__ task_param,
                     const float* __restrict__ gw_img, const float* __restrict__ gb_img,
                     const float* __restrict__ gw_txt, const float* __restrict__ gb_txt,
                     const float* __restrict__ tgw, const float* __restrict__ tgb,
                     const float* __restrict__ alpha_p, const int* __restrict__ is_text_p,
                     float4* __restrict__ sel_w, float* __restrict__ prob_part,
                     int* __restrict__ count_part) {
  int gid = blockIdx.x;
  if (gid < 8192) {
    // w1: R=D, C=H; (x:H/64=64, y:D/64=16, e:8)
    int gx = gid & 63, gy = (gid >> 6) & 15, e = gid >> 10;
    conv_block(w1 + (size_t)e * D_ * H_, w1b + (size_t)e * D_ * H_,
               D_, H_, gy * 64, gx * 64);
    return;
  }
  // ---- gating ----
  int bid = gid - 8192;
  __shared__ float wprob[4][8];
  __shared__ int wcnt[4][8];
  int wid = threadIdx.x >> 6, lane = threadIdx.x & 63;
  int t = bid * 4 + wid;
  int b = t & (B_ - 1);
  int it = is_text_p[0];
  const float* gw = it ? gw_txt : gw_img;
  const float* gb = it ? gb_txt : gb_img;
  float alpha = alpha_p[0];
  const float* xr = x + (size_t)t * D_;
  const float* tp = task_param + (size_t)b * D_;
  float acc[8] = {0,0,0,0,0,0,0,0};
  float tac[8] = {0,0,0,0,0,0,0,0};
  for (int i = 0; i < D_/64; ++i) {
    int d = i * 64 + lane;
    float xv = xr[d], tv = tp[d];
#pragma unroll
    for (int e = 0; e < 8; ++e) {
      acc[e] += xv * gw[d*8 + e];
      tac[e] += tv * tgw[d*8 + e];
    }
  }
#pragma unroll
  for (int e = 0; e < 8; ++e) {
#pragma unroll
    for (int off = 32; off > 0; off >>= 1) {
      acc[e] += __shfl_xor(acc[e], off);
      tac[e] += __shfl_xor(tac[e], off);
    }
  }
  float lg[8];
#pragma unroll
  for (int e = 0; e < 8; ++e)
    lg[e] = (1.0f - alpha) * (acc[e] + gb[e]) + alpha * (tac[e] + tgb[e]);
  float m = lg[0];
#pragma unroll
  for (int e = 1; e < 8; ++e) m = fmaxf(m, lg[e]);
  float pr[8], ps = 0.f;
#pragma unroll
  for (int e = 0; e < 8; ++e) { pr[e] = expf(lg[e] - m); ps += pr[e]; }
  float inv = 1.0f / ps;
  int i0 = 0; float v0 = lg[0];
#pragma unroll
  for (int e = 1; e < 8; ++e) if (lg[e] > v0) { v0 = lg[e]; i0 = e; }
  int i1 = -1; float v1 = -1e30f;
#pragma unroll
  for (int e = 0; e < 8; ++e) if (e != i0 && lg[e] > v1) { v1 = lg[e]; i1 = e; }
  float ex = expf(v1 - v0);
  float w0 = 1.0f / (1.0f + ex), w1v = ex / (1.0f + ex);
  if (lane == 0) {
    sel_w[t] = make_float4(__int_as_float(i0), __int_as_float(i1), w0, w1v);
#pragma unroll
    for (int e = 0; e < 8; ++e) {
      wprob[wid][e] = pr[e] * inv;
      wcnt[wid][e] = (i0 == e) + (i1 == e);
    }
  }
  __syncthreads();
  if (threadIdx.x < 8) {
    int e = threadIdx.x;
    prob_part[bid * 8 + e] = wprob[0][e] + wprob[1][e] + wprob[2][e] + wprob[3][e];
    count_part[bid * 8 + e] = wcnt[0][e] + wcnt[1][e] + wcnt[2][e] + wcnt[3][e];
  }
}

// ---------------------------------------------------------------------------
// Finalize: deterministic reduce -> counts/offs/cursors + unit tables + l_aux
// GEMM2 now KSPLIT=4 (quarter-K units) for finer critical-path balance.
// ---------------------------------------------------------------------------
__global__ void finalize(const float* __restrict__ prob_part, const int* __restrict__ count_part,
                         int* __restrict__ meta, float* __restrict__ laux_out) {
  __shared__ float ps_[256];
  __shared__ int cs_[256];
  int t = threadIdx.x;
  int e = t & 7, s = t >> 3;
  float p = 0.f; int c = 0;
  for (int b = s; b < 1024; b += 32) { p += prob_part[b*8 + e]; c += count_part[b*8 + e]; }
  ps_[t] = p; cs_[t] = c;
  __syncthreads();
  for (int st = 16; st > 0; st >>= 1) {
    if (s < st) { ps_[t] += ps_[t + st*8]; cs_[t] += cs_[t + st*8]; }
    __syncthreads();
  }
  if (t == 0) {
    int off = 0; float laux = 0.f;
    int u1 = 0, u2 = 0;
    for (int ee = 0; ee < 8; ++ee) {
      int cnt = cs_[ee];
      meta[ee] = cnt;          // counts
      meta[8 + ee] = off;      // offs
      meta[16 + ee] = off;     // cursors
      int nb = (cnt + 255) >> 8;
      meta[24 + ee] = nb;      // nbx
      meta[32 + ee] = u1;      // ub1 (GEMM1: 16 panels x nb)
      meta[41 + ee] = u2;      // ub2 (GEMM2: 4 panels x nb x 4 ksplit)
      u1 += 16 * nb;
      u2 += 16 * nb;
      off += cnt;
      laux += (ps_[ee] * (1.0f/4096.0f)) * ((float)cnt * (1.0f/4096.0f));
    }
    meta[32 + 8] = u1;         // ub1[8] = U1 total (gemm units only)
    meta[41 + 8] = u2;         // ub2[8] = U2 total
    meta[50] = 0;              // tick1
    meta[51] = 0;              // tick2
    *laux_out = laux;
  }
}

// ---------------------------------------------------------------------------
// Scatter + gather: assign bucket slots, record token->pair map, gather bf16 rows
// ---------------------------------------------------------------------------
__global__ void scatter_gather(const float* __restrict__ x, const float4* __restrict__ sel_w,
                               int* __restrict__ cursors, float* __restrict__ pair_w,
                               int* __restrict__ pair_idx, u16* __restrict__ Xg) {
  int wid = threadIdx.x >> 6, lane = threadIdx.x & 63;
  int t = blockIdx.x * 4 + wid;
  float4 sw = sel_w[t];
  int s0 = __float_as_int(sw.x), s1 = __float_as_int(sw.y);
  int p0 = 0, p1 = 0;
  if (lane == 0) {
    p0 = atomicAdd(&cursors[s0], 1);
    p1 = atomicAdd(&cursors[s1], 1);
  }
  p0 = __shfl(p0, 0); p1 = __shfl(p1, 0);
  if (lane == 0) {
    pair_w[p0] = sw.z; pair_w[p1] = sw.w;
    pair_idx[t*2] = p0; pair_idx[t*2+1] = p1;
  }
  const float* xr = x + (size_t)t * D_;
  u16* d0 = Xg + (size_t)p0 * D_;
  u16* d1 = Xg + (size_t)p1 * D_;
#pragma unroll
  for (int i = 0; i < 4; ++i) {
    int c = i * 256 + lane * 4;
    float4 v = *(const float4*)(xr + c);
    ushort4 o;
    o.x = f2bf(v.x); o.y = f2bf(v.y); o.z = f2bf(v.z); o.w = f2bf(v.w);
    *(ushort4*)(d0 + c) = o;
    *(ushort4*)(d1 + c) = o;
  }
}

// ---------------------------------------------------------------------------
// Grouped GEMM, 256x256 tile, BK=64, 8 waves, 2-phase, ticketed (R10-exact
// core: the measured-best schedule). New: DOCONV (GEMM1 only) appends 4096
// w2-conversion units (128x64 transpose tiles, full 512 threads, As-as-
// scratch) AFTER the gemm units in the same ticket space — blocks finishing
// gemm work early tail-fill with conv; conv HBM traffic hides under other
// blocks' MFMA instead of occupying a serial kernel. Pure-per-unit -> any
// grab order correct; ticket-top __syncthreads fences LDS reuse.
//
// LDS swizzle (verified 0 conflicts): 8 x 16B slots/row, phys = kk^(row&7);
// staging dest linear in tid (rule 21), global source carries the inverse.
// __launch_bounds__(512,2): CUDA min-blocks semantics -> VGPR cap 128.
// EPI==1 writes bf16 K-part buffers (summed in combine).
// ---------------------------------------------------------------------------
template<int EPI, int KDIM, int KLEN, int NOUT, int NPANEL, int KSPLIT, bool DOCONV>
__global__ __launch_bounds__(512, 2)
void gemm256(const u16* __restrict__ Tok, const u16* __restrict__ Wt,
             int* __restrict__ meta, const float* __restrict__ pair_w,
             u16* __restrict__ Hout, u16* __restrict__ Cout,
             const float* __restrict__ w2f, u16* __restrict__ w2b) {
  const int* offs = meta + 8;
  const int* nbx  = meta + 24;
  const int* ub   = (EPI == 0) ? meta + 32 : meta + 41;
  int* tick       = meta + ((EPI == 0) ? 50 : 51);

  __shared__ u16 As[2][16384];   // 256 x 64 bf16 = 32 KB per buffer
  __shared__ u16 Bs[2][16384];
  __shared__ int s_u;
  int t = threadIdx.x, lane = t & 63, wid = t >> 6;
  int wf = wid & 1, wt = wid >> 1;

  // staging map: i covers slots [i*512 + t]; row = slot>>3,
  // kk = (slot&7) ^ (row&7) (involution).
  int goff[4]; int ldso[4];
#pragma unroll
  for (int i = 0; i < 4; ++i) {
    int slot = i * 512 + t;
    int row = slot >> 3;
    int kk = (slot & 7) ^ (row & 7);
    goff[i] = row * KDIM + kk * 8;
    ldso[i] = slot * 8;
  }

  // fragment read offsets (u16): phys = (row*8 + (kk ^ (row&7)))*8
  int aoff[8][2], boff[4][2];
#pragma unroll
  for (int r = 0; r < 8; ++r) {
    int row = wf * 128 + r * 16 + (lane & 15);
#pragma unroll
    for (int h = 0; h < 2; ++h) {
      int kk = h * 4 + (lane >> 4);
      aoff[r][h] = (row * 8 + (kk ^ (row & 7))) * 8;
    }
  }
#pragma unroll
  for (int f = 0; f < 4; ++f) {
    int row = wt * 64 + f * 16 + (lane & 15);
#pragma unroll
    for (int h = 0; h < 2; ++h) {
      int kk = h * 4 + (lane >> 4);
      boff[f][h] = (row * 8 + (kk ^ (row & 7))) * 8;
    }
  }

  constexpr int NT = KLEN / 64;
  int lr = lane & 15, lg4 = (lane >> 4) * 4;
  int Ugemm = ub[8];
  int Utot = DOCONV ? (Ugemm + 4096) : Ugemm;

  for (;;) {
    if (t == 0) s_u = atomicAdd(tick, 1);
    __syncthreads();               // broadcast ticket; fences LDS reuse
    int u = s_u;
    if (u >= Utot) break;

    if (DOCONV && u >= Ugemm) {
      // ---- w2 conversion unit: fp32 [H][D] tile (128r x 64c) -> bf16 [D][H]
      int cu = u - Ugemm;          // [0, 4096)
      int e = cu >> 9;             // 512 units/expert (32 rblk x 16 cblk)
      int loc = cu & 511;
      int rb = loc >> 4, cb = loc & 15;
      int r0 = rb * 128, c0 = cb * 64;
      const float* src = w2f + (size_t)e * H_ * D_;
      u16* dst = w2b + (size_t)e * H_ * D_;
      float* tile = (float*)&As[0][0];   // 128 x 67 f32 = 34304 B (< 64 KB)
#pragma unroll
      for (int p = 0; p < 4; ++p) {
        int idx = p * 512 + t;           // 0..2047
        int r = idx >> 4;                // 0..127
        int cq = (idx & 15) * 4;         // 0..60
        float4 v = *(const float4*)(src + (size_t)(r0 + r) * D_ + c0 + cq);
        float* tr = tile + r * 67 + cq;
        tr[0] = v.x; tr[1] = v.y; tr[2] = v.z; tr[3] = v.w;
      }
      __syncthreads();
      int c = t >> 3, rq0 = (t & 7) * 16;
#pragma unroll
      for (int j = 0; j < 16; j += 4) {
        ushort4 o;
        o.x = f2bf(tile[(rq0 + j + 0) * 67 + c]);
        o.y = f2bf(tile[(rq0 + j + 1) * 67 + c]);
        o.z = f2bf(tile[(rq0 + j + 2) * 67 + c]);
        o.w = f2bf(tile[(rq0 + j + 3) * 67 + c]);
        *(ushort4*)(dst + (size_t)(c0 + c) * H_ + r0 + rq0 + j) = o;
      }
      continue;
    }

    // decode gemm unit: expert (prefix scan), then panel-major local
    int e = 0;
    while (u >= ub[e + 1]) ++e;
    int ul = u - ub[e];
    int nb = nbx[e];
    int panel = ul / (nb * KSPLIT);
    int rem   = ul - panel * (nb * KSPLIT);
    int bx    = rem / KSPLIT;
    int ks    = rem - bx * KSPLIT;
    int ne  = meta[e];
    int off = offs[e];
    int kbase = ks * KLEN;
    u16* Cpart = Cout + (size_t)ks * P_ * D_;
    const u16* Wg = Wt + (size_t)e * NOUT * KDIM + (size_t)panel * 256 * KDIM + kbase;
    const u16* Tg = Tok + (size_t)(off + bx * 256) * KDIM + kbase;

    f32x4 acc[8][4] = {};
    // prologue: stage K-tile 0 into buf 0
#pragma unroll
    for (int i = 0; i < 4; ++i) {
      __builtin_amdgcn_global_load_lds(
          (const __attribute__((address_space(1))) void*)(Wg + goff[i]),
          (__attribute__((address_space(3))) void*)(&As[0][ldso[i]]), 16, 0, 0);
      __builtin_amdgcn_global_load_lds(
          (const __attribute__((address_space(1))) void*)(Tg + goff[i]),
          (__attribute__((address_space(3))) void*)(&Bs[0][ldso[i]]), 16, 0, 0);
    }
    __syncthreads();
    int cur = 0;
    for (int tt = 0; tt < NT; ++tt) {
      if (tt + 1 < NT) {
        int k0 = (tt + 1) * 64;
        int nbuf = cur ^ 1;
#pragma unroll
        for (int i = 0; i < 4; ++i) {
          __builtin_amdgcn_global_load_lds(
              (const __attribute__((address_space(1))) void*)(Wg + goff[i] + k0),
              (__attribute__((address_space(3))) void*)(&As[nbuf][ldso[i]]), 16, 0, 0);
          __builtin_amdgcn_global_load_lds(
              (const __attribute__((address_space(1))) void*)(Tg + goff[i] + k0),
              (__attribute__((address_space(3))) void*)(&Bs[nbuf][ldso[i]]), 16, 0, 0);
        }
      }
      const u16* Ab = &As[cur][0]; const u16* Bb = &Bs[cur][0];
#pragma unroll
      for (int h = 0; h < 2; ++h) {
        s16x8 a[8], b[4];
#pragma unroll
        for (int r = 0; r < 8; ++r) a[r] = *(const s16x8*)(Ab + aoff[r][h]);
#pragma unroll
        for (int f = 0; f < 4; ++f) b[f] = *(const s16x8*)(Bb + boff[f][h]);
#pragma unroll
        for (int r = 0; r < 8; ++r)
#pragma unroll
          for (int f = 0; f < 4; ++f)
            acc[r][f] = __builtin_amdgcn_mfma_f32_16x16x32_bf16(a[r], b[f], acc[r][f], 0, 0, 0);
      }
      __syncthreads();
      cur ^= 1;
    }

    // epilogue: token = wt*64 + f*16 + lr (col), feature = wf*128 + r*16 + lg4 + j
#pragma unroll
    for (int f = 0; f < 4; ++f) {
      int tokl = bx * 256 + wt * 64 + f * 16 + lr;
      if (tokl >= ne) continue;
      size_t grow = (size_t)(off + tokl);
      if (EPI == 0) {
#pragma unroll
        for (int r = 0; r < 8; ++r) {
          ushort4 o;
          o.x = f2bf(gelu_fast(acc[r][f][0]));
          o.y = f2bf(gelu_fast(acc[r][f][1]));
          o.z = f2bf(gelu_fast(acc[r][f][2]));
          o.w = f2bf(gelu_fast(acc[r][f][3]));
          *(ushort4*)(Hout + grow * NOUT + panel * 256 + wf * 128 + r * 16 + lg4) = o;
        }
      } else {
        float w = pair_w[grow];
#pragma unroll
        for (int r = 0; r < 8; ++r) {
          ushort4 o;
          o.x = f2bf(acc[r][f][0] * w); o.y = f2bf(acc[r][f][1] * w);
          o.z = f2bf(acc[r][f][2] * w); o.w = f2bf(acc[r][f][3] * w);
          *(ushort4*)(Cpart + grow * NOUT + panel * 256 + wf * 128 + r * 16 + lg4) = o;
        }
      }
    }
  }
}

// ---------------------------------------------------------------------------
// Combine: out[token] = sum over 2 pairs x 4 K-parts (bf16 parts -> f32)
// ---------------------------------------------------------------------------
__global__ void combine(const u16* __restrict__ pair_out, const int* __restrict__ pair_idx,
                        float* __restrict__ out) {
  int t = blockIdx.x;
  int p0 = pair_idx[t*2], p1 = pair_idx[t*2+1];
  int c = threadIdx.x * 4;
  float ox = 0.f, oy = 0.f, oz = 0.f, ow = 0.f;
#pragma unroll
  for (int part = 0; part < 4; ++part) {
    const u16* pp = pair_out + (size_t)part * P_ * D_;
    ushort4 a = *(const ushort4*)(pp + (size_t)p0 * D_ + c);
    ushort4 b = *(const ushort4*)(pp + (size_t)p1 * D_ + c);
    ox += bf2f(a.x) + bf2f(b.x);
    oy += bf2f(a.y) + bf2f(b.y);
    oz += bf2f(a.z) + bf2f(b.z);
    ow += bf2f(a.w) + bf2f(b.w);
  }
  float4 o; o.x = ox; o.y = oy; o.z = oz; o.w = ow;
  *(float4*)(out + (size_t)t * D_ + c) = o;
}

// ---------------------------------------------------------------------------
// Workspace layout (bytes):
//   w1b  [E][H][D] bf16 @ 0           (67108864)  <- aliased by pair_out parts
//   w2b  [E][D][H] bf16 @ 67108864    (67108864)
//   Xg   [PPAD][D] bf16 @ 134217728   (17301504)
//   Hb   [PPAD][H] bf16 @ 151519232   (69206016)
//   small buffers @ 220725248
//   pair_out: 4 parts x [P_][D_] bf16 @ 0 (67108864 exactly, aliases dead w1b)
// ---------------------------------------------------------------------------
extern "C" void kernel_launch(void* const* d_in, const int* in_sizes, int n_in,
                              void* d_out, int out_size, void* d_ws, size_t ws_size,
                              hipStream_t stream) {
  const float* inputs      = (const float*)d_in[0];
  const float* task_param  = (const float*)d_in[1];
  const float* gate_img_w  = (const float*)d_in[2];
  const float* gate_img_b  = (const float*)d_in[3];
  const float* gate_txt_w  = (const float*)d_in[4];
  const float* gate_txt_b  = (const float*)d_in[5];
  const float* task_gate_w = (const float*)d_in[6];
  const float* task_gate_b = (const float*)d_in[7];
  const float* alpha       = (const float*)d_in[8];
  const float* w1          = (const float*)d_in[9];
  const float* w2          = (const float*)d_in[10];
  const int*   is_text     = (const int*)d_in[11];
  float* out = (float*)d_out;

  char* ws = (char*)d_ws;
  u16* w1b = (u16*)(ws + 0);
  u16* w2b = (u16*)(ws + 67108864);
  u16* Xg  = (u16*)(ws + 134217728);
  u16* Hb  = (u16*)(ws + 151519232);
  float4* sel_w   = (float4*)(ws + 220725248);
  float* pair_w   = (float*)(ws + 220725248 + 65536);
  int* pair_idx   = (int*)(ws + 220725248 + 98816);
  float* prob_part= (float*)(ws + 220725248 + 131584);
  int* count_part = (int*)(ws + 220725248 + 164352);
  int* meta       = (int*)(ws + 220725248 + 197120);
  u16* pair_out   = (u16*)(ws + 0);  // 4 bf16 parts, aliases dead w1b

  // PREP: w1 conv (8192 blocks) + gating (1024). w2 conv folded into GEMM1.
  prep<<<dim3(9216), 256, 0, stream>>>(w1, w1b,
      inputs, task_param, gate_img_w, gate_img_b, gate_txt_w, gate_txt_b,
      task_gate_w, task_gate_b, alpha, is_text, sel_w, prob_part, count_part);
  finalize<<<dim3(1), 256, 0, stream>>>(prob_part, count_part, meta,
      out + (size_t)T_ * D_);
  scatter_gather<<<dim3(T_/4), 256, 0, stream>>>(inputs, sel_w, meta + 16, pair_w, pair_idx, Xg);
  // GEMM1: Tok=Xg, W=w1b; K=1024 (NT=16), 16 panels; + 4096 w2-conv units.
  gemm256<0, D_, D_, H_, 16, 1, true><<<dim3(256), 512, 0, stream>>>(
      Xg, w1b, meta, pair_w, Hb, (u16*)nullptr, w2, w2b);
  // GEMM2: Tok=Hb, W=w2b; K=4096 split 4x1024 (NT=16), 4 panels.
  gemm256<1, H_, H_/4, D_, 4, 4, false><<<dim3(256), 512, 0, stream>>>(
      Hb, w2b, meta, pair_w, (u16*)nullptr, pair_out, (const float*)nullptr, (u16*)nullptr);
  combine<<<dim3(T_), 256, 0, stream>>>(pair_out, pair_idx, out);
}